// Round 5
// baseline (337.451 us; speedup 1.0000x reference)
//
#include <hip/hip_runtime.h>
#include <hip/hip_bf16.h>

#define BATCH   256
#define NLAYERS 32
#define HID     1024
#define INTER   2816
#define BK      64

typedef __attribute__((ext_vector_type(8))) short bf16x8;
typedef __attribute__((ext_vector_type(4))) float f32x4;
typedef __attribute__((ext_vector_type(4))) int   i32x4;

__device__ __forceinline__ ushort f2bf(float f) {
  __hip_bfloat16 b = __float2bfloat16(f);   // RNE
  return *reinterpret_cast<ushort*>(&b);
}

__device__ __forceinline__ bf16x8 cvt8(f32x4 a, f32x4 b) {
  bf16x8 o;
  o[0] = (short)f2bf(a[0]); o[1] = (short)f2bf(a[1]);
  o[2] = (short)f2bf(a[2]); o[3] = (short)f2bf(a[3]);
  o[4] = (short)f2bf(b[0]); o[5] = (short)f2bf(b[1]);
  o[6] = (short)f2bf(b[2]); o[7] = (short)f2bf(b[3]);
  return o;
}

// ---------------------------------------------------------------------------
// Kernel 0: pack h (B,N,D) fp32 -> Xp[n][b][d] bf16 (contiguous per layer).
// ---------------------------------------------------------------------------
__global__ __launch_bounds__(256) void k_pack(
    const float* __restrict__ h, ushort* __restrict__ Xp) {
  const int r    = blockIdx.x * 4 + (threadIdx.x >> 6);   // 0..8191 = b*32+n
  const int lane = threadIdx.x & 63;
  const int ro   = ((r & 31) * 256 + (r >> 5)) * 1024;    // out row = n*256+b
  const float* src = h + (size_t)r * 1024 + lane * 4;
  ushort* dst      = Xp + ro + lane * 4;
#pragma unroll
  for (int g = 0; g < 4; ++g) {
    f32x4 v = *(const f32x4*)(src + g * 256);
    ushort4 o;
    o.x = f2bf(v[0]); o.y = f2bf(v[1]); o.z = f2bf(v[2]); o.w = f2bf(v[3]);
    *(ushort4*)(dst + g * 256) = o;
  }
}

// ---------------------------------------------------------------------------
// Kernel 1: act = silu(X Wg^T) * (X Wu^T).  BM=256, BN=64 inter-cols, BK=64.
// B-tile = 128 rows (rows 0..63 = Wg[i0..i0+64), rows 64..127 = Wu[...]) x 64
// = 32 KB fp32 HBM per step (3200 cyc) vs ~1500 cyc LDS -> HBM-phase
// dominates the step.  Grid = 32*44 = 1408 blocks (5.5/CU, 88 block-steps/CU
// = k_down's measured-at-roofline shape).  Waves 4M x 2N; acc[m][n][gu]:
// gate and up for the SAME (b,i) live in one thread -> silu fused, no
// exchange.  Same 2-barrier / XOR-swizzle / 1-deep-prefetch skeleton as
// k_down.  __launch_bounds__(512,4): VGPR<=128 -> 2 resident blocks/CU.
// ---------------------------------------------------------------------------
__global__ __launch_bounds__(512, 4) void k_gateup(
    const ushort* __restrict__ Xp, const float* __restrict__ Wg,
    const float* __restrict__ Wu, ushort* __restrict__ act) {
  const int bid   = blockIdx.x;
  const int layer = bid / (INTER / 64);    // 44 itiles/layer
  const int it    = bid % (INTER / 64);
  const int i0    = it * 64;
  const int tid   = threadIdx.x;
  const int lane  = tid & 63;
  const int wave  = tid >> 6;
  const int wm    = wave >> 1;             // 0..3 : 64 batch rows
  const int wn    = wave & 1;              // 0..1 : 32 inter cols

  __shared__ ushort lds[BATCH * BK + 128 * BK];   // 32 KB A + 16 KB B = 48 KB
  ushort* Al = lds;
  ushort* Wl = lds + BATCH * BK;

  f32x4 acc[4][2][2] = {};                 // [m][n][0=gate,1=up]

  // A staging: 2048 granules of 8 bf16; 4/thread (i32x4 copy)
  int aldst[4];
  const ushort* asrc[4];
#pragma unroll
  for (int r = 0; r < 4; ++r) {
    int g = tid + 512 * r;
    int arow = g >> 3, akc = g & 7;
    aldst[r] = arow * BK + ((akc ^ (arow & 7)) << 3);
    asrc[r] = Xp + ((size_t)layer * BATCH + arow) * HID + akc * 8;
  }
  // B staging: 1024 granules (128 rows x 8 slots); 2/thread (gate + up rows)
  const int wrow = tid >> 3, wsl = tid & 7;          // gate row, slot
  const int wldstG = wrow * BK + ((wsl ^ (wrow & 7)) << 3);
  const int wrowU  = 64 + wrow;
  const int wldstU = wrowU * BK + ((wsl ^ (wrowU & 7)) << 3);
  const float* gsrc = Wg + (size_t)layer * INTER * HID + (size_t)(i0 + wrow) * HID + wsl * 8;
  const float* usrc = Wu + (size_t)layer * INTER * HID + (size_t)(i0 + wrow) * HID + wsl * 8;

  i32x4 ra[4];
  f32x4 rg[2], ru[2];
#pragma unroll
  for (int r = 0; r < 4; ++r) ra[r] = *(const i32x4*)asrc[r];
  rg[0] = *(const f32x4*)gsrc; rg[1] = *(const f32x4*)(gsrc + 4);
  ru[0] = *(const f32x4*)usrc; ru[1] = *(const f32x4*)(usrc + 4);

  const int r16 = lane & 15;
  const int g4  = lane >> 4;

  const int NK = HID / BK;                 // 16
  for (int k = 0; k < NK; ++k) {
    __syncthreads();
#pragma unroll
    for (int r = 0; r < 4; ++r) *(i32x4*)&Al[aldst[r]] = ra[r];
    *(bf16x8*)&Wl[wldstG] = cvt8(rg[0], rg[1]);
    *(bf16x8*)&Wl[wldstU] = cvt8(ru[0], ru[1]);
    __syncthreads();

    if (k + 1 < NK) {
      int off = (k + 1) * BK;
#pragma unroll
      for (int r = 0; r < 4; ++r) ra[r] = *(const i32x4*)(asrc[r] + off);
      rg[0] = *(const f32x4*)(gsrc + off); rg[1] = *(const f32x4*)(gsrc + off + 4);
      ru[0] = *(const f32x4*)(usrc + off); ru[1] = *(const f32x4*)(usrc + off + 4);
    }

#pragma unroll
    for (int ks = 0; ks < 2; ++ks) {
      const int kg = ks * 4 + g4;
      bf16x8 af[4];
#pragma unroll
      for (int m = 0; m < 4; ++m) {
        int row = wm * 64 + m * 16 + r16;
        af[m] = *(bf16x8*)&Al[row * BK + ((kg ^ (row & 7)) << 3)];
      }
#pragma unroll
      for (int n = 0; n < 2; ++n) {
        int rowG = wn * 32 + n * 16 + r16;        // 0..63  (gate)
        int rowU = 64 + rowG;                     // 64..127 (up)
        bf16x8 bg = *(bf16x8*)&Wl[rowG * BK + ((kg ^ (rowG & 7)) << 3)];
        bf16x8 bu = *(bf16x8*)&Wl[rowU * BK + ((kg ^ (rowU & 7)) << 3)];
#pragma unroll
        for (int m = 0; m < 4; ++m) {
          acc[m][n][0] = __builtin_amdgcn_mfma_f32_16x16x32_bf16(af[m], bg, acc[m][n][0], 0, 0, 0);
          acc[m][n][1] = __builtin_amdgcn_mfma_f32_16x16x32_bf16(af[m], bu, acc[m][n][1], 0, 0, 0);
        }
      }
    }
  }

  // epilogue: silu(gate)*up, thread-local. C/D: col=lane&15, row=(lane>>4)*4+r
  const int r4 = (lane >> 4) * 4;
#pragma unroll
  for (int m = 0; m < 4; ++m)
#pragma unroll
    for (int n = 0; n < 2; ++n)
#pragma unroll
      for (int r = 0; r < 4; ++r) {
        float g = acc[m][n][0][r];
        float u = acc[m][n][1][r];
        float a = (g / (1.f + __expf(-g))) * u;
        int b = wm * 64 + m * 16 + r4 + r;
        int i = i0 + wn * 32 + n * 16 + r16;
        act[((size_t)layer * BATCH + b) * INTER + i] = f2bf(a);
      }
}

// ---------------------------------------------------------------------------
// Kernel 2: out[b][layer][d] = act Wd^T.  UNCHANGED (measured ~65 us, at its
// HBM roofline: Wd 369 MB + out 32 MB; act reads served by L3).
// ---------------------------------------------------------------------------
__global__ __launch_bounds__(512) void k_down(
    const ushort* __restrict__ act, const float* __restrict__ Wd,
    float* __restrict__ out) {
  const int bid   = blockIdx.x;
  const int layer = bid / (HID / 64);
  const int dtile = bid % (HID / 64);
  const int d0    = dtile * 64;
  const int tid   = threadIdx.x;
  const int lane  = tid & 63;
  const int wave  = tid >> 6;
  const int wm    = wave >> 1;
  const int wn    = wave & 1;

  __shared__ ushort lds[BATCH * BK + 64 * BK];       // 40 KiB
  ushort* Al = lds;
  ushort* Wl = lds + BATCH * BK;

  f32x4 acc[4][2] = {};

  int aldst[4];
  const ushort* asrc[4];
#pragma unroll
  for (int r = 0; r < 4; ++r) {
    int g = tid + 512 * r;
    int arow = g >> 3, akc = g & 7;
    aldst[r] = arow * BK + ((akc ^ (arow & 7)) << 3);
    asrc[r] = act + ((size_t)layer * BATCH + arow) * INTER + akc * 8;
  }
  const int wrow = tid >> 3, wkc = tid & 7;
  const int wldst = wrow * BK + ((wkc ^ (wrow & 7)) << 3);
  const float* wsrc = Wd + (size_t)layer * HID * INTER + (size_t)(d0 + wrow) * INTER + wkc * 8;

  i32x4 ra[4];
  f32x4 rw[2];

#pragma unroll
  for (int r = 0; r < 4; ++r) ra[r] = *(const i32x4*)asrc[r];
  rw[0] = *(const f32x4*)wsrc; rw[1] = *(const f32x4*)(wsrc + 4);

  const int NK = INTER / BK;   // 44
  for (int k = 0; k < NK; ++k) {
    __syncthreads();
#pragma unroll
    for (int r = 0; r < 4; ++r) *(i32x4*)&Al[aldst[r]] = ra[r];
    *(bf16x8*)&Wl[wldst] = cvt8(rw[0], rw[1]);
    __syncthreads();

    if (k + 1 < NK) {
      int off = (k + 1) * BK;
#pragma unroll
      for (int r = 0; r < 4; ++r) ra[r] = *(const i32x4*)(asrc[r] + off);
      rw[0] = *(const f32x4*)(wsrc + off); rw[1] = *(const f32x4*)(wsrc + off + 4);
    }

#pragma unroll
    for (int ks = 0; ks < 2; ++ks) {
      const int kg = ks * 4 + (lane >> 4);
      bf16x8 af[4];
#pragma unroll
      for (int m = 0; m < 4; ++m) {
        int row = wm * 64 + m * 16 + (lane & 15);
        af[m] = *(bf16x8*)&Al[row * BK + ((kg ^ (row & 7)) << 3)];
      }
#pragma unroll
      for (int n = 0; n < 2; ++n) {
        int row = wn * 32 + n * 16 + (lane & 15);
        bf16x8 bw = *(bf16x8*)&Wl[row * BK + ((kg ^ (row & 7)) << 3)];
#pragma unroll
        for (int m = 0; m < 4; ++m)
          acc[m][n] = __builtin_amdgcn_mfma_f32_16x16x32_bf16(af[m], bw, acc[m][n], 0, 0, 0);
      }
    }
  }

  const int c16 = lane & 15;
  const int r4  = (lane >> 4) * 4;
#pragma unroll
  for (int m = 0; m < 4; ++m)
#pragma unroll
    for (int n = 0; n < 2; ++n)
#pragma unroll
      for (int r = 0; r < 4; ++r) {
        int b = wm * 64 + m * 16 + r4 + r;
        int d = d0 + wn * 32 + n * 16 + c16;
        out[(size_t)b * (NLAYERS * HID) + (size_t)layer * HID + d] = acc[m][n][r];
      }
}

extern "C" void kernel_launch(void* const* d_in, const int* in_sizes, int n_in,
                              void* d_out, int out_size, void* d_ws, size_t ws_size,
                              hipStream_t stream) {
  const float* h  = (const float*)d_in[0];
  const float* Wg = (const float*)d_in[1];
  const float* Wu = (const float*)d_in[2];
  const float* Wd = (const float*)d_in[3];
  float* out  = (float*)d_out;
  ushort* act = (ushort*)d_ws;                                   // 46.1 MB
  ushort* Xp  = (ushort*)d_ws + (size_t)NLAYERS * BATCH * INTER; // +16.8 MB

  hipLaunchKernelGGL(k_pack, dim3(BATCH * NLAYERS / 4), dim3(256), 0, stream,
                     h, Xp);
  hipLaunchKernelGGL(k_gateup, dim3(NLAYERS * (INTER / 64)), dim3(512), 0, stream,
                     Xp, Wg, Wu, act);
  hipLaunchKernelGGL(k_down, dim3(NLAYERS * (HID / 64)), dim3(512), 0, stream,
                     act, Wd, out);
}

// Round 6
// 324.807 us; speedup vs baseline: 1.0389x; 1.0389x over previous
//
#include <hip/hip_runtime.h>
#include <hip/hip_bf16.h>

#define BATCH   256
#define NLAYERS 32
#define HID     1024
#define INTER   2816

typedef __attribute__((ext_vector_type(8))) short bf16x8;
typedef __attribute__((ext_vector_type(4))) float f32x4;
typedef __attribute__((ext_vector_type(4))) int   i32x4;

__device__ __forceinline__ ushort f2bf(float f) {
  __hip_bfloat16 b = __float2bfloat16(f);   // RNE
  return *reinterpret_cast<ushort*>(&b);
}

__device__ __forceinline__ bf16x8 cvt8(f32x4 a, f32x4 b) {
  bf16x8 o;
  o[0] = (short)f2bf(a[0]); o[1] = (short)f2bf(a[1]);
  o[2] = (short)f2bf(a[2]); o[3] = (short)f2bf(a[3]);
  o[4] = (short)f2bf(b[0]); o[5] = (short)f2bf(b[1]);
  o[6] = (short)f2bf(b[2]); o[7] = (short)f2bf(b[3]);
  return o;
}

// ---------------------------------------------------------------------------
// Kernel 0: h (b,n,d) fp32 -> Xp2 bf16, PRE-SWIZZLED + K-TILED for
// global_load_lds (G21: linear LDS dest + inverse-swizzled source).
// Layout: Xp2[layer][t][row=b][slot f]*8bf16, where slot f holds original
// k-granule kg = f ^ ((row>>1)&3), t = k/32 tile.  One (layer,t) chunk =
// 256*4 granules * 16 B = 16 KB = exactly one A-tile LDS image.
// Swizzle derivation: ds_read_b128 af: 16 consecutive rows, fixed kg ->
// slot-col (4*row + f) % 8 covers all 8 per 8 rows -> 2-way max (free, m136).
// ---------------------------------------------------------------------------
__global__ __launch_bounds__(256) void k_pack(
    const float* __restrict__ h, ushort* __restrict__ Xp2) {
  const int pr    = blockIdx.x * 4 + (threadIdx.x >> 6);  // 0..8191
  const int b     = pr >> 5;                              // batch row
  const int layer = pr & 31;
  const int lane  = threadIdx.x & 63;
  const float* src = h + (size_t)b * (NLAYERS * HID) + (size_t)layer * HID;
  ushort* dstL = Xp2 + (size_t)layer * (32 * 8192);       // 32 t-chunks
#pragma unroll
  for (int c = 0; c < 2; ++c) {
    int gi = lane + c * 64;              // granule 0..127 of this row
    int t  = gi >> 2, kg = gi & 3;
    f32x4 v0 = *(const f32x4*)(src + t * 32 + kg * 8);
    f32x4 v1 = *(const f32x4*)(src + t * 32 + kg * 8 + 4);
    int f = kg ^ ((b >> 1) & 3);
    *(bf16x8*)(dstL + (size_t)t * 8192 + b * 32 + f * 8) = cvt8(v0, v1);
  }
}

// ---------------------------------------------------------------------------
// Kernel 1: act = silu(X Wg^T) * (X Wu^T).  BM=256, BN=64, BK=32, NK=32.
// 2-phase counted-vmcnt schedule (T3/T4 minimum form):
//   step t: {global_load_lds A(t+1) -> Al[nxt]  (async, no regs)
//            global f32x4 loads B(t+1) -> regs} issued FIRST;
//           compute on Al[cur]/Bl[cur] (8 ds_read_b128 + 16 MFMA);
//           cvt8 + ds_write B(t+1) -> Bl[nxt];
//           ONE __syncthreads (its vmcnt(0) drains loads issued a full
//           compute-phase earlier -> latency hidden).
// LDS 48 KB: Al 2x16 KB (linear image of pre-swizzled Xp2), Bl 2x8 KB.
// B tile = 128 rows (64 Wg + 64 Wu) x 32 k; acc[m][n][gu] thread-local silu.
// ---------------------------------------------------------------------------
__global__ __launch_bounds__(512, 4) void k_gateup(
    const ushort* __restrict__ Xp2, const float* __restrict__ Wg,
    const float* __restrict__ Wu, ushort* __restrict__ act) {
  const int bid   = blockIdx.x;
  const int layer = bid / (INTER / 64);    // 44 itiles/layer
  const int it    = bid % (INTER / 64);
  const int i0    = it * 64;
  const int tid   = threadIdx.x;
  const int lane  = tid & 63;
  const int wave  = tid >> 6;
  const int wm    = wave >> 1;             // 0..3 : 64 batch rows
  const int wn    = wave & 1;              // 0..1 : 32 inter cols
  const int r16   = lane & 15;
  const int g4    = lane >> 4;             // k-granule 0..3 (K=32)

  __shared__ ushort Al[2][256 * 32];       // 2 x 16 KB
  __shared__ ushort Bl[2][128 * 32];       // 2 x  8 KB

  f32x4 acc[4][2][2] = {};                 // [m][n][0=gate,1=up]

  // B staging: one 8-float granule per thread (rows 0..63 Wg, 64..127 Wu)
  const int brow  = tid >> 2;              // 0..127
  const int bslot = tid & 3;
  const int bdst  = brow * 32 + ((bslot ^ ((brow >> 1) & 3)) << 3);
  const float* bsrc = (brow < 64 ? Wg + (size_t)(i0 + brow) * HID
                                 : Wu + (size_t)(i0 + brow - 64) * HID)
                      + (size_t)layer * INTER * HID + bslot * 8;

  // A async-copy source (pre-swizzled, contiguous per t-chunk)
  const ushort* agbase = Xp2 + (size_t)layer * (32 * 8192);

  // ---- prologue: tile 0
#pragma unroll
  for (int c = 0; c < 2; ++c)
    __builtin_amdgcn_global_load_lds(
        (const void*)(agbase + (wave * 128 + c * 64 + lane) * 8),
        (void*)&Al[0][(wave * 128 + c * 64) * 8], 16, 0, 0);
  {
    f32x4 rb0 = *(const f32x4*)bsrc;
    f32x4 rb1 = *(const f32x4*)(bsrc + 4);
    *(bf16x8*)&Bl[0][bdst] = cvt8(rb0, rb1);
  }
  __syncthreads();

  const int NK = HID / 32;                 // 32
  int cur = 0;
  for (int t = 0; t < NK; ++t) {
    const int nxt = cur ^ 1;
    f32x4 rb[2];
    if (t + 1 < NK) {
      // issue next A tile straight into LDS (stays in VMEM queue all phase)
#pragma unroll
      for (int c = 0; c < 2; ++c)
        __builtin_amdgcn_global_load_lds(
            (const void*)(agbase + (size_t)(t + 1) * 8192 +
                          (wave * 128 + c * 64 + lane) * 8),
            (void*)&Al[nxt][(wave * 128 + c * 64) * 8], 16, 0, 0);
      // issue next B weights into regs
      rb[0] = *(const f32x4*)(bsrc + (t + 1) * 32);
      rb[1] = *(const f32x4*)(bsrc + (t + 1) * 32 + 4);
    }

    // ---- compute on current buffers
    bf16x8 af[4];
#pragma unroll
    for (int m = 0; m < 4; ++m) {
      int row = wm * 64 + m * 16 + r16;
      af[m] = *(bf16x8*)&Al[cur][row * 32 + ((g4 ^ ((row >> 1) & 3)) << 3)];
    }
#pragma unroll
    for (int n = 0; n < 2; ++n) {
      int rg_ = wn * 32 + n * 16 + r16;          // gate row 0..63
      int ru_ = 64 + rg_;                        // up   row 64..127
      bf16x8 bg = *(bf16x8*)&Bl[cur][rg_ * 32 + ((g4 ^ ((rg_ >> 1) & 3)) << 3)];
      bf16x8 bu = *(bf16x8*)&Bl[cur][ru_ * 32 + ((g4 ^ ((ru_ >> 1) & 3)) << 3)];
#pragma unroll
      for (int m = 0; m < 4; ++m) {
        acc[m][n][0] = __builtin_amdgcn_mfma_f32_16x16x32_bf16(af[m], bg, acc[m][n][0], 0, 0, 0);
        acc[m][n][1] = __builtin_amdgcn_mfma_f32_16x16x32_bf16(af[m], bu, acc[m][n][1], 0, 0, 0);
      }
    }

    if (t + 1 < NK)
      *(bf16x8*)&Bl[nxt][bdst] = cvt8(rb[0], rb[1]);  // waits only its own loads
    __syncthreads();                                  // drains A(t+1) too
    cur = nxt;
  }

  // epilogue: silu(gate)*up, thread-local. C/D: col=lane&15, row=(lane>>4)*4+r
  const int r4 = (lane >> 4) * 4;
#pragma unroll
  for (int m = 0; m < 4; ++m)
#pragma unroll
    for (int n = 0; n < 2; ++n)
#pragma unroll
      for (int r = 0; r < 4; ++r) {
        float g = acc[m][n][0][r];
        float u = acc[m][n][1][r];
        float a = (g / (1.f + __expf(-g))) * u;
        int b = wm * 64 + m * 16 + r4 + r;
        int i = i0 + wn * 32 + n * 16 + r16;
        act[((size_t)layer * BATCH + b) * INTER + i] = f2bf(a);
      }
}

// ---------------------------------------------------------------------------
// Kernel 2: out[b][layer][d] = act Wd^T.  UNCHANGED (measured ~65 us, at its
// HBM roofline: Wd 369 MB + out 32 MB; act reads served by L3).
// ---------------------------------------------------------------------------
#define BK 64

__global__ __launch_bounds__(512) void k_down(
    const ushort* __restrict__ act, const float* __restrict__ Wd,
    float* __restrict__ out) {
  const int bid   = blockIdx.x;
  const int layer = bid / (HID / 64);
  const int dtile = bid % (HID / 64);
  const int d0    = dtile * 64;
  const int tid   = threadIdx.x;
  const int lane  = tid & 63;
  const int wave  = tid >> 6;
  const int wm    = wave >> 1;
  const int wn    = wave & 1;

  __shared__ ushort lds[BATCH * BK + 64 * BK];       // 40 KiB
  ushort* Al = lds;
  ushort* Wl = lds + BATCH * BK;

  f32x4 acc[4][2] = {};

  int aldst[4];
  const ushort* asrc[4];
#pragma unroll
  for (int r = 0; r < 4; ++r) {
    int g = tid + 512 * r;
    int arow = g >> 3, akc = g & 7;
    aldst[r] = arow * BK + ((akc ^ (arow & 7)) << 3);
    asrc[r] = act + ((size_t)layer * BATCH + arow) * INTER + akc * 8;
  }
  const int wrow = tid >> 3, wkc = tid & 7;
  const int wldst = wrow * BK + ((wkc ^ (wrow & 7)) << 3);
  const float* wsrc = Wd + (size_t)layer * HID * INTER + (size_t)(d0 + wrow) * INTER + wkc * 8;

  i32x4 ra[4];
  f32x4 rw[2];

#pragma unroll
  for (int r = 0; r < 4; ++r) ra[r] = *(const i32x4*)asrc[r];
  rw[0] = *(const f32x4*)wsrc; rw[1] = *(const f32x4*)(wsrc + 4);

  const int NK = INTER / BK;   // 44
  for (int k = 0; k < NK; ++k) {
    __syncthreads();
#pragma unroll
    for (int r = 0; r < 4; ++r) *(i32x4*)&Al[aldst[r]] = ra[r];
    *(bf16x8*)&Wl[wldst] = cvt8(rw[0], rw[1]);
    __syncthreads();

    if (k + 1 < NK) {
      int off = (k + 1) * BK;
#pragma unroll
      for (int r = 0; r < 4; ++r) ra[r] = *(const i32x4*)(asrc[r] + off);
      rw[0] = *(const f32x4*)(wsrc + off); rw[1] = *(const f32x4*)(wsrc + off + 4);
    }

#pragma unroll
    for (int ks = 0; ks < 2; ++ks) {
      const int kg = ks * 4 + (lane >> 4);
      bf16x8 af[4];
#pragma unroll
      for (int m = 0; m < 4; ++m) {
        int row = wm * 64 + m * 16 + (lane & 15);
        af[m] = *(bf16x8*)&Al[row * BK + ((kg ^ (row & 7)) << 3)];
      }
#pragma unroll
      for (int n = 0; n < 2; ++n) {
        int row = wn * 32 + n * 16 + (lane & 15);
        bf16x8 bw = *(bf16x8*)&Wl[row * BK + ((kg ^ (row & 7)) << 3)];
#pragma unroll
        for (int m = 0; m < 4; ++m)
          acc[m][n] = __builtin_amdgcn_mfma_f32_16x16x32_bf16(af[m], bw, acc[m][n], 0, 0, 0);
      }
    }
  }

  const int c16 = lane & 15;
  const int r4  = (lane >> 4) * 4;
#pragma unroll
  for (int m = 0; m < 4; ++m)
#pragma unroll
    for (int n = 0; n < 2; ++n)
#pragma unroll
      for (int r = 0; r < 4; ++r) {
        int b = wm * 64 + m * 16 + r4 + r;
        int d = d0 + wn * 32 + n * 16 + c16;
        out[(size_t)b * (NLAYERS * HID) + (size_t)layer * HID + d] = acc[m][n][r];
      }
}

extern "C" void kernel_launch(void* const* d_in, const int* in_sizes, int n_in,
                              void* d_out, int out_size, void* d_ws, size_t ws_size,
                              hipStream_t stream) {
  const float* h  = (const float*)d_in[0];
  const float* Wg = (const float*)d_in[1];
  const float* Wu = (const float*)d_in[2];
  const float* Wd = (const float*)d_in[3];
  float* out  = (float*)d_out;
  ushort* act = (ushort*)d_ws;                                    // 46.1 MB
  ushort* Xp2 = (ushort*)d_ws + (size_t)NLAYERS * BATCH * INTER;  // +16.8 MB

  hipLaunchKernelGGL(k_pack, dim3(BATCH * NLAYERS / 4), dim3(256), 0, stream,
                     h, Xp2);
  hipLaunchKernelGGL(k_gateup, dim3(NLAYERS * (INTER / 64)), dim3(512), 0, stream,
                     Xp2, Wg, Wu, act);
  hipLaunchKernelGGL(k_down, dim3(NLAYERS * (HID / 64)), dim3(512), 0, stream,
                     act, Wd, out);
}